// Round 5
// baseline (584.310 us; speedup 1.0000x reference)
//
#include <hip/hip_runtime.h>
#include <hip/hip_bf16.h>

#define H_DIM 768
#define S_LEN 128
#define BK 64
#define NT 12  // 768 / 64 K-tiles

typedef __attribute__((ext_vector_type(8))) short short8;
typedef __attribute__((ext_vector_type(4))) float f32x4;

__device__ __forceinline__ void gload_lds16(const void* g, void* l) {
  __builtin_amdgcn_global_load_lds(
      (const __attribute__((address_space(1))) unsigned int*)g,
      (__attribute__((address_space(3))) unsigned int*)l, 16, 0, 0);
}

// ---------------- Kernel 1: per-token L2 normalize, fp32 -> bf16 (both tensors) ----------------
__global__ __launch_bounds__(256) void norm_bf16_kernel(
    const float* __restrict__ x1, const float* __restrict__ x2,
    unsigned short* __restrict__ xn1, unsigned short* __restrict__ xn2) {
  const int gid = blockIdx.x;
  const float* row;
  unsigned short* orow;
  if (gid < 8192) { row = x1 + (size_t)gid * H_DIM; orow = xn1 + (size_t)gid * H_DIM; }
  else            { row = x2 + (size_t)(gid - 8192) * H_DIM; orow = xn2 + (size_t)(gid - 8192) * H_DIM; }
  const int tid = threadIdx.x;
  float4 v = make_float4(0.f, 0.f, 0.f, 0.f);
  float ss = 0.f;
  if (tid < 192) {
    v = reinterpret_cast<const float4*>(row)[tid];
    ss = v.x * v.x + v.y * v.y + v.z * v.z + v.w * v.w;
  }
#pragma unroll
  for (int o = 32; o > 0; o >>= 1) ss += __shfl_down(ss, o);
  __shared__ float ws[4];
  if ((tid & 63) == 0) ws[tid >> 6] = ss;
  __syncthreads();
  const float scale = 1.0f / sqrtf(ws[0] + ws[1] + ws[2] + ws[3]);
  if (tid < 192) {
    union { ushort4 u; __hip_bfloat16 h[4]; } o;
    o.h[0] = __float2bfloat16(v.x * scale);
    o.h[1] = __float2bfloat16(v.y * scale);
    o.h[2] = __float2bfloat16(v.z * scale);
    o.h[3] = __float2bfloat16(v.w * scale);
    reinterpret_cast<ushort4*>(orow)[tid] = o.u;
  }
}

// A-stage: 2 gload_lds/thread into buf BUF (16 KB tile). Linear LDS dest,
// inverse-swizzled GLOBAL source chunk (rule 21).
#define STAGE_A(KN, BUF)                                          \
  {                                                               \
    gload_lds16(Ag + asrc0 + (KN), Al + (BUF)*8192 + ad0);        \
    gload_lds16(Ag + asrc1 + (KN), Al + (BUF)*8192 + ad1);        \
  }

// B fragments for K-tile at element offset KN -> registers (8 dwordx4/lane from L2)
#define LOADB(BV, KN)                                             \
  {                                                               \
    BV[0][0] = *reinterpret_cast<const short8*>(B0p + (KN));      \
    BV[0][1] = *reinterpret_cast<const short8*>(B1p + (KN));      \
    BV[0][2] = *reinterpret_cast<const short8*>(B2p + (KN));      \
    BV[0][3] = *reinterpret_cast<const short8*>(B3p + (KN));      \
    BV[1][0] = *reinterpret_cast<const short8*>(B0p + (KN) + 32); \
    BV[1][1] = *reinterpret_cast<const short8*>(B1p + (KN) + 32); \
    BV[1][2] = *reinterpret_cast<const short8*>(B2p + (KN) + 32); \
    BV[1][3] = *reinterpret_cast<const short8*>(B3p + (KN) + 32); \
  }

// One K-tile step: {prefetch A(kt+1)->LDS[NXT], B(kt+1)->BVN | compute kt from
// LDS[CUR] x BVC | vmcnt(8) (A landed, B flies) | barrier}. One barrier/K-tile:
// barrier arrival implies av ds_reads retired (MFMA consumed them), so the WAR
// on LDS[NXT] next step is safe; per-wave vmcnt BEFORE the barrier closes the
// cross-wave RAW on LDS[NXT].
#define STEP(CUR, NXT, BVC, BVN, KT, PF)                                      \
  {                                                                           \
    if (PF) {                                                                 \
      const int kn = ((KT) + 1) * BK;                                         \
      STAGE_A(kn, NXT);                                                       \
      __builtin_amdgcn_sched_barrier(0); /* pin A-issue before B-issue */     \
      LOADB(BVN, kn);                                                         \
      __builtin_amdgcn_sched_barrier(0);                                      \
    }                                                                         \
    _Pragma("unroll")                                                         \
    for (int kf = 0; kf < 2; ++kf) {                                          \
      short8 av[4];                                                           \
      _Pragma("unroll")                                                       \
      for (int i = 0; i < 4; ++i) {                                           \
        const int r = wm * 64 + i * 16 + rl;                                  \
        const int slot = (kf * 4 + g) ^ (r & 7); /* swizzled read */          \
        av[i] = *reinterpret_cast<const short8*>(&Al[(CUR)*8192 + r * 64 + slot * 8]); \
      }                                                                       \
      __builtin_amdgcn_s_setprio(1);                                          \
      _Pragma("unroll")                                                       \
      for (int i = 0; i < 4; ++i)                                             \
        _Pragma("unroll")                                                     \
        for (int j = 0; j < 4; ++j)                                           \
          acc[i][j] = __builtin_amdgcn_mfma_f32_16x16x32_bf16(                \
              av[i], BVC[kf][j], acc[i][j], 0, 0, 0);                         \
      __builtin_amdgcn_s_setprio(0);                                          \
    }                                                                         \
    if (PF) {                                                                 \
      asm volatile("s_waitcnt vmcnt(8)" ::: "memory");                        \
      __builtin_amdgcn_s_barrier();                                           \
    }                                                                         \
  }

// ---------------- Kernel 2: one block = (a, {b0,b1}), 128x256 tile ----------------
// 8 waves 2x4: wave (wm,wn) owns rows wm*64..+64, cols wn*64..+64.
// A double-buffered in LDS (32 KB); B double-buffered in REGISTERS from L2.
__global__ __launch_bounds__(512, 4) void rwmd_kernel(
    const unsigned short* __restrict__ xn1, const unsigned short* __restrict__ xn2,
    const int* __restrict__ mask1, const int* __restrict__ mask2,
    float* __restrict__ out) {
  __shared__ __align__(16) unsigned short Al[2 * S_LEN * BK];  // 32 KB, 2 bufs
  __shared__ int m1s[S_LEN], m2s[2 * S_LEN];
  __shared__ float rpart[4][S_LEN];      // [wn][row] partial row-max
  __shared__ float cpart[2][2 * S_LEN];  // [wm][col] partial col-max

  const int a = blockIdx.x >> 5;   // 64 a's
  const int bp = blockIdx.x & 31;  // 32 b-pairs
  const int tid = threadIdx.x;
  const int lane = tid & 63;
  const int w = tid >> 6;
  const int wm = w >> 2, wn = w & 3;
  const int g = lane >> 4, rl = lane & 15;

  const unsigned short* Ag = xn1 + (size_t)a * (S_LEN * H_DIM);
  const unsigned short* Bg = xn2 + (size_t)bp * (2 * S_LEN * H_DIM);  // 256 rows

  if (tid < S_LEN) m1s[tid] = mask1[a * S_LEN + tid];
  else if (tid < 3 * S_LEN) m2s[tid - S_LEN] = mask2[bp * 2 * S_LEN + (tid - S_LEN)];

  // per-thread A-stage addressing (chunk s = q*512+tid; row = s>>3; src chunk XOR-swizzled)
  const int s0 = tid, s1 = 512 + tid;
  const int ar0 = s0 >> 3, ar1 = s1 >> 3;
  const size_t asrc0 = (size_t)ar0 * H_DIM + (size_t)(((s0 & 7) ^ (ar0 & 7)) * 8);
  const size_t asrc1 = (size_t)ar1 * H_DIM + (size_t)(((s1 & 7) ^ (ar1 & 7)) * 8);
  const int ad0 = s0 * 8, ad1 = s1 * 8;

  // B fragment row pointers (one per j; g-offset folded in)
  const unsigned short* B0p = Bg + (size_t)(wn * 64 +  0 + rl) * H_DIM + g * 8;
  const unsigned short* B1p = Bg + (size_t)(wn * 64 + 16 + rl) * H_DIM + g * 8;
  const unsigned short* B2p = Bg + (size_t)(wn * 64 + 32 + rl) * H_DIM + g * 8;
  const unsigned short* B3p = Bg + (size_t)(wn * 64 + 48 + rl) * H_DIM + g * 8;

  f32x4 acc[4][4];
#pragma unroll
  for (int i = 0; i < 4; ++i)
#pragma unroll
    for (int j = 0; j < 4; ++j) acc[i][j] = (f32x4){0.f, 0.f, 0.f, 0.f};
  short8 bva[2][4], bvb[2][4];

  // prologue: tile 0 (A->LDS buf0, B->bva); full drain once per block
  STAGE_A(0, 0);
  __builtin_amdgcn_sched_barrier(0);
  LOADB(bva, 0);
  asm volatile("s_waitcnt vmcnt(0)" ::: "memory");
  __builtin_amdgcn_s_barrier();

#pragma unroll 1
  for (int t = 0; t < NT / 2; ++t) {
    STEP(0, 1, bva, bvb, 2 * t, true);          // kt even: 0..10, always prefetch
    STEP(1, 0, bvb, bva, 2 * t + 1, (t < 5));   // kt odd: last (11) has no prefetch
  }

  // ---- in-register masked reductions ----
  // acc[i][j][r]: row = wm*64 + i*16 + g*4 + r, col = wn*64 + j*16 + rl
#pragma unroll
  for (int i = 0; i < 4; ++i) {
#pragma unroll
    for (int r = 0; r < 4; ++r) {
      float pm = -INFINITY;
#pragma unroll
      for (int j = 0; j < 4; ++j) {
        const int col = wn * 64 + j * 16 + rl;
        pm = fmaxf(pm, m2s[col] ? acc[i][j][r] : -INFINITY);
      }
#pragma unroll
      for (int o = 1; o < 16; o <<= 1) pm = fmaxf(pm, __shfl_xor(pm, o));
      if (rl == 0) rpart[wn][wm * 64 + i * 16 + g * 4 + r] = pm;
    }
  }
#pragma unroll
  for (int j = 0; j < 4; ++j) {
    float cm = -INFINITY;
#pragma unroll
    for (int i = 0; i < 4; ++i)
#pragma unroll
      for (int r = 0; r < 4; ++r) {
        const int row = wm * 64 + i * 16 + g * 4 + r;
        cm = fmaxf(cm, m1s[row] ? acc[i][j][r] : -INFINITY);
      }
    cm = fmaxf(cm, __shfl_xor(cm, 16));
    cm = fmaxf(cm, __shfl_xor(cm, 32));
    if (g == 0) cpart[wm][wn * 64 + j * 16 + rl] = cm;
  }
  __syncthreads();

  // ---- final masked means: wave 0 -> b0, wave 1 -> b1 ----
  if (w < 2) {
    float v1 = 0.f, c1 = 0.f, v2 = 0.f, c2 = 0.f;
#pragma unroll
    for (int t = 0; t < 2; ++t) {
      const int r = lane + t * 64;
      if (m1s[r]) { v1 += fmaxf(rpart[2 * w][r], rpart[2 * w + 1][r]); c1 += 1.f; }
      const int c = w * 128 + lane + t * 64;
      if (m2s[c]) { v2 += fmaxf(cpart[0][c], cpart[1][c]); c2 += 1.f; }
    }
#pragma unroll
    for (int o = 32; o > 0; o >>= 1) {
      v1 += __shfl_down(v1, o); c1 += __shfl_down(c1, o);
      v2 += __shfl_down(v2, o); c2 += __shfl_down(c2, o);
    }
    if (lane == 0) out[a * 64 + bp * 2 + w] = 0.5f * (v1 / c1 + v2 / c2);
  }
}

extern "C" void kernel_launch(void* const* d_in, const int* in_sizes, int n_in,
                              void* d_out, int out_size, void* d_ws, size_t ws_size,
                              hipStream_t stream) {
  const float* x1 = (const float*)d_in[0];
  const int* mask1 = (const int*)d_in[1];
  const float* x2 = (const float*)d_in[2];
  const int* mask2 = (const int*)d_in[3];
  float* out = (float*)d_out;

  unsigned short* xn1 = (unsigned short*)d_ws;
  unsigned short* xn2 = xn1 + (size_t)64 * 128 * 768;

  norm_bf16_kernel<<<16384, 256, 0, stream>>>(x1, x2, xn1, xn2);
  rwmd_kernel<<<64 * 32, 512, 0, stream>>>(xn1, xn2, mask1, mask2, out);
}

// Round 6
// 268.371 us; speedup vs baseline: 2.1772x; 2.1772x over previous
//
#include <hip/hip_runtime.h>
#include <hip/hip_bf16.h>

#define H_DIM 768
#define S_LEN 128
#define BK 64
#define NT 12  // 768 / 64 K-tiles

typedef __attribute__((ext_vector_type(8))) short short8;
typedef __attribute__((ext_vector_type(4))) float f32x4;

__device__ __forceinline__ void gload_lds16(const void* g, void* l) {
  __builtin_amdgcn_global_load_lds(
      (const __attribute__((address_space(1))) unsigned int*)g,
      (__attribute__((address_space(3))) unsigned int*)l, 16, 0, 0);
}

// ---------------- Kernel 1: per-token L2 normalize, fp32 -> bf16 (both tensors) ----------------
__global__ __launch_bounds__(256) void norm_bf16_kernel(
    const float* __restrict__ x1, const float* __restrict__ x2,
    unsigned short* __restrict__ xn1, unsigned short* __restrict__ xn2) {
  const int gid = blockIdx.x;
  const float* row;
  unsigned short* orow;
  if (gid < 8192) { row = x1 + (size_t)gid * H_DIM; orow = xn1 + (size_t)gid * H_DIM; }
  else            { row = x2 + (size_t)(gid - 8192) * H_DIM; orow = xn2 + (size_t)(gid - 8192) * H_DIM; }
  const int tid = threadIdx.x;
  float4 v = make_float4(0.f, 0.f, 0.f, 0.f);
  float ss = 0.f;
  if (tid < 192) {
    v = reinterpret_cast<const float4*>(row)[tid];
    ss = v.x * v.x + v.y * v.y + v.z * v.z + v.w * v.w;
  }
#pragma unroll
  for (int o = 32; o > 0; o >>= 1) ss += __shfl_down(ss, o);
  __shared__ float ws[4];
  if ((tid & 63) == 0) ws[tid >> 6] = ss;
  __syncthreads();
  const float scale = 1.0f / sqrtf(ws[0] + ws[1] + ws[2] + ws[3]);
  if (tid < 192) {
    union { ushort4 u; __hip_bfloat16 h[4]; } o;
    o.h[0] = __float2bfloat16(v.x * scale);
    o.h[1] = __float2bfloat16(v.y * scale);
    o.h[2] = __float2bfloat16(v.z * scale);
    o.h[3] = __float2bfloat16(v.w * scale);
    reinterpret_cast<ushort4*>(orow)[tid] = o.u;
  }
}

// A-stage: 2 gload_lds/thread into buf BUF (16 KB tile). Linear LDS dest,
// inverse-swizzled GLOBAL source chunk (rule 21).
#define STAGE_A(KN, BUF)                                          \
  {                                                               \
    gload_lds16(Ag + asrc0 + (KN), Al + (BUF)*8192 + ad0);        \
    gload_lds16(Ag + asrc1 + (KN), Al + (BUF)*8192 + ad1);        \
  }

// B fragments for K-tile at element offset KN -> registers (8 dwordx4/lane from L2)
#define LOADB(BV, KN)                                             \
  {                                                               \
    BV[0][0] = *reinterpret_cast<const short8*>(B0p + (KN));      \
    BV[0][1] = *reinterpret_cast<const short8*>(B1p + (KN));      \
    BV[0][2] = *reinterpret_cast<const short8*>(B2p + (KN));      \
    BV[0][3] = *reinterpret_cast<const short8*>(B3p + (KN));      \
    BV[1][0] = *reinterpret_cast<const short8*>(B0p + (KN) + 32); \
    BV[1][1] = *reinterpret_cast<const short8*>(B1p + (KN) + 32); \
    BV[1][2] = *reinterpret_cast<const short8*>(B2p + (KN) + 32); \
    BV[1][3] = *reinterpret_cast<const short8*>(B3p + (KN) + 32); \
  }

// One K-tile step: {prefetch A(kt+1)->LDS[NXT] (2 vmem) then B(kt+1)->BVN (8 vmem)
// | compute kt from LDS[CUR] x BVC | vmcnt(8): the 2 A-DMAs retired, B flies |
// barrier}. End-of-step barrier separates step t compute (reads LDS[CUR]) from
// step t+1 staging (writes LDS[CUR]); MFMA consumption forces ds_read retirement
// before the barrier. One barrier per K-tile; B is per-wave private (no barrier).
#define STEP(CUR, NXT, BVC, BVN, KT, PF)                                      \
  {                                                                           \
    if (PF) {                                                                 \
      const int kn = ((KT) + 1) * BK;                                         \
      STAGE_A(kn, NXT);                                                       \
      __builtin_amdgcn_sched_barrier(0); /* pin A-issue before B-issue */     \
      LOADB(BVN, kn);                                                         \
      __builtin_amdgcn_sched_barrier(0);                                      \
    }                                                                         \
    _Pragma("unroll")                                                         \
    for (int kf = 0; kf < 2; ++kf) {                                          \
      short8 av[4];                                                           \
      _Pragma("unroll")                                                       \
      for (int i = 0; i < 4; ++i) {                                           \
        const int r = wm * 64 + i * 16 + rl;                                  \
        const int slot = (kf * 4 + g) ^ (r & 7); /* swizzled read */          \
        av[i] = *reinterpret_cast<const short8*>(&Al[(CUR)*8192 + r * 64 + slot * 8]); \
      }                                                                       \
      __builtin_amdgcn_s_setprio(1);                                          \
      _Pragma("unroll")                                                       \
      for (int i = 0; i < 4; ++i)                                             \
        _Pragma("unroll")                                                     \
        for (int j = 0; j < 4; ++j)                                           \
          acc[i][j] = __builtin_amdgcn_mfma_f32_16x16x32_bf16(                \
              av[i], BVC[kf][j], acc[i][j], 0, 0, 0);                         \
      __builtin_amdgcn_s_setprio(0);                                          \
    }                                                                         \
    if (PF) {                                                                 \
      asm volatile("s_waitcnt vmcnt(8)" ::: "memory");                        \
      __builtin_amdgcn_s_barrier();                                           \
    }                                                                         \
  }

// ---------------- Kernel 2: one block = (a, {b0,b1}), 128x256 tile ----------------
// 8 waves 2x4: wave (wm,wn) owns rows wm*64..+64, cols wn*64..+64.
// A double-buffered in LDS (32 KB); B double-buffered in REGISTERS from L2.
// launch_bounds(512,2): VGPR cap 256 — kernel needs ~170-230; (512,4)'s 128 cap
// caused the round-5 spill catastrophe (1.7 GB scratch writes).
__global__ __launch_bounds__(512, 2) void rwmd_kernel(
    const unsigned short* __restrict__ xn1, const unsigned short* __restrict__ xn2,
    const int* __restrict__ mask1, const int* __restrict__ mask2,
    float* __restrict__ out) {
  __shared__ __align__(16) unsigned short Al[2 * S_LEN * BK];  // 32 KB, 2 bufs
  __shared__ int m1s[S_LEN], m2s[2 * S_LEN];
  __shared__ float rpart[4][S_LEN];      // [wn][row] partial row-max
  __shared__ float cpart[2][2 * S_LEN];  // [wm][col] partial col-max

  const int a = blockIdx.x >> 5;   // 64 a's
  const int bp = blockIdx.x & 31;  // 32 b-pairs
  const int tid = threadIdx.x;
  const int lane = tid & 63;
  const int w = tid >> 6;
  const int wm = w >> 2, wn = w & 3;
  const int g = lane >> 4, rl = lane & 15;

  const unsigned short* Ag = xn1 + (size_t)a * (S_LEN * H_DIM);
  const unsigned short* Bg = xn2 + (size_t)bp * (2 * S_LEN * H_DIM);  // 256 rows

  if (tid < S_LEN) m1s[tid] = mask1[a * S_LEN + tid];
  else if (tid < 3 * S_LEN) m2s[tid - S_LEN] = mask2[bp * 2 * S_LEN + (tid - S_LEN)];

  // per-thread A-stage addressing (chunk s = q*512+tid; row = s>>3; src chunk XOR-swizzled)
  const int s0 = tid, s1 = 512 + tid;
  const int ar0 = s0 >> 3, ar1 = s1 >> 3;
  const size_t asrc0 = (size_t)ar0 * H_DIM + (size_t)(((s0 & 7) ^ (ar0 & 7)) * 8);
  const size_t asrc1 = (size_t)ar1 * H_DIM + (size_t)(((s1 & 7) ^ (ar1 & 7)) * 8);
  const int ad0 = s0 * 8, ad1 = s1 * 8;

  // B fragment row pointers (one per j; g-offset folded in)
  const unsigned short* B0p = Bg + (size_t)(wn * 64 +  0 + rl) * H_DIM + g * 8;
  const unsigned short* B1p = Bg + (size_t)(wn * 64 + 16 + rl) * H_DIM + g * 8;
  const unsigned short* B2p = Bg + (size_t)(wn * 64 + 32 + rl) * H_DIM + g * 8;
  const unsigned short* B3p = Bg + (size_t)(wn * 64 + 48 + rl) * H_DIM + g * 8;

  f32x4 acc[4][4];
#pragma unroll
  for (int i = 0; i < 4; ++i)
#pragma unroll
    for (int j = 0; j < 4; ++j) acc[i][j] = (f32x4){0.f, 0.f, 0.f, 0.f};
  short8 bva[2][4], bvb[2][4];

  // prologue: tile 0 (A->LDS buf0, B->bva); full drain once per block
  STAGE_A(0, 0);
  __builtin_amdgcn_sched_barrier(0);
  LOADB(bva, 0);
  asm volatile("s_waitcnt vmcnt(0)" ::: "memory");
  __builtin_amdgcn_s_barrier();

#pragma unroll 1
  for (int t = 0; t < NT / 2; ++t) {
    STEP(0, 1, bva, bvb, 2 * t, true);          // kt even: 0..10, always prefetch
    STEP(1, 0, bvb, bva, 2 * t + 1, (t < 5));   // kt odd: last (11) has no prefetch
  }

  // ---- in-register masked reductions ----
  // acc[i][j][r]: row = wm*64 + i*16 + g*4 + r, col = wn*64 + j*16 + rl
#pragma unroll
  for (int i = 0; i < 4; ++i) {
#pragma unroll
    for (int r = 0; r < 4; ++r) {
      float pm = -INFINITY;
#pragma unroll
      for (int j = 0; j < 4; ++j) {
        const int col = wn * 64 + j * 16 + rl;
        pm = fmaxf(pm, m2s[col] ? acc[i][j][r] : -INFINITY);
      }
#pragma unroll
      for (int o = 1; o < 16; o <<= 1) pm = fmaxf(pm, __shfl_xor(pm, o));
      if (rl == 0) rpart[wn][wm * 64 + i * 16 + g * 4 + r] = pm;
    }
  }
#pragma unroll
  for (int j = 0; j < 4; ++j) {
    float cm = -INFINITY;
#pragma unroll
    for (int i = 0; i < 4; ++i)
#pragma unroll
      for (int r = 0; r < 4; ++r) {
        const int row = wm * 64 + i * 16 + g * 4 + r;
        cm = fmaxf(cm, m1s[row] ? acc[i][j][r] : -INFINITY);
      }
    cm = fmaxf(cm, __shfl_xor(cm, 16));
    cm = fmaxf(cm, __shfl_xor(cm, 32));
    if (g == 0) cpart[wm][wn * 64 + j * 16 + rl] = cm;
  }
  __syncthreads();

  // ---- final masked means: wave 0 -> b0, wave 1 -> b1 ----
  if (w < 2) {
    float v1 = 0.f, c1 = 0.f, v2 = 0.f, c2 = 0.f;
#pragma unroll
    for (int t = 0; t < 2; ++t) {
      const int r = lane + t * 64;
      if (m1s[r]) { v1 += fmaxf(rpart[2 * w][r], rpart[2 * w + 1][r]); c1 += 1.f; }
      const int c = w * 128 + lane + t * 64;
      if (m2s[c]) { v2 += fmaxf(cpart[0][c], cpart[1][c]); c2 += 1.f; }
    }
#pragma unroll
    for (int o = 32; o > 0; o >>= 1) {
      v1 += __shfl_down(v1, o); c1 += __shfl_down(c1, o);
      v2 += __shfl_down(v2, o); c2 += __shfl_down(c2, o);
    }
    if (lane == 0) out[a * 64 + bp * 2 + w] = 0.5f * (v1 / c1 + v2 / c2);
  }
}

extern "C" void kernel_launch(void* const* d_in, const int* in_sizes, int n_in,
                              void* d_out, int out_size, void* d_ws, size_t ws_size,
                              hipStream_t stream) {
  const float* x1 = (const float*)d_in[0];
  const int* mask1 = (const int*)d_in[1];
  const float* x2 = (const float*)d_in[2];
  const int* mask2 = (const int*)d_in[3];
  float* out = (float*)d_out;

  unsigned short* xn1 = (unsigned short*)d_ws;
  unsigned short* xn2 = xn1 + (size_t)64 * 128 * 768;

  norm_bf16_kernel<<<16384, 256, 0, stream>>>(x1, x2, xn1, xn2);
  rwmd_kernel<<<64 * 32, 512, 0, stream>>>(xn1, xn2, mask1, mask2, out);
}

// Round 7
// 170.441 us; speedup vs baseline: 3.4282x; 1.5746x over previous
//
#include <hip/hip_runtime.h>
#include <hip/hip_bf16.h>

#define H_DIM 768
#define S_LEN 128
#define BK 64
#define NT 12  // 768 / 64 K-tiles

typedef __attribute__((ext_vector_type(8))) short short8;
typedef __attribute__((ext_vector_type(4))) float f32x4;

__device__ __forceinline__ void gload_lds16(const void* g, void* l) {
  __builtin_amdgcn_global_load_lds(
      (const __attribute__((address_space(1))) unsigned int*)g,
      (__attribute__((address_space(3))) unsigned int*)l, 16, 0, 0);
}

// ---------------- Kernel 1: per-token L2 normalize, fp32 -> bf16 ----------------
// x1 -> row-major xn1 (A operand, staged via DMA).
// x2 -> FRAGMENT-PACKED xn2p: granule layout [b][kc][t], kc = K/8 (96), t = token
// (128), 16B granules. A wave's bv load then reads 256B contiguous per g-group
// (4 dense segments/instr instead of 16 sparse rows).
__global__ __launch_bounds__(256) void norm_bf16_kernel(
    const float* __restrict__ x1, const float* __restrict__ x2,
    unsigned short* __restrict__ xn1, unsigned short* __restrict__ xn2p) {
  const int gid = blockIdx.x;
  const bool isA = (gid < 8192);
  const float* row = isA ? (x1 + (size_t)gid * H_DIM)
                         : (x2 + (size_t)(gid - 8192) * H_DIM);
  const int tid = threadIdx.x;
  float4 v = make_float4(0.f, 0.f, 0.f, 0.f);
  float ss = 0.f;
  if (tid < 192) {
    v = reinterpret_cast<const float4*>(row)[tid];
    ss = v.x * v.x + v.y * v.y + v.z * v.z + v.w * v.w;
  }
#pragma unroll
  for (int o = 32; o > 0; o >>= 1) ss += __shfl_down(ss, o);
  __shared__ float ws[4];
  if ((tid & 63) == 0) ws[tid >> 6] = ss;
  __syncthreads();
  const float scale = 1.0f / sqrtf(ws[0] + ws[1] + ws[2] + ws[3]);
  if (isA) {
    if (tid < 192) {
      union { ushort4 u; __hip_bfloat16 h[4]; } o;
      o.h[0] = __float2bfloat16(v.x * scale);
      o.h[1] = __float2bfloat16(v.y * scale);
      o.h[2] = __float2bfloat16(v.z * scale);
      o.h[3] = __float2bfloat16(v.w * scale);
      reinterpret_cast<ushort4*>(xn1 + (size_t)gid * H_DIM)[tid] = o.u;
    }
  } else {
    const int tok = gid - 8192;
    const int b = tok >> 7, t = tok & 127;
    if (tid < 96) {  // one 16B granule (8 elems) per thread
      const float4 u0 = reinterpret_cast<const float4*>(row)[tid * 2];
      const float4 u1 = reinterpret_cast<const float4*>(row)[tid * 2 + 1];
      union { short8 s; __hip_bfloat16 h[8]; } o;
      o.h[0] = __float2bfloat16(u0.x * scale);
      o.h[1] = __float2bfloat16(u0.y * scale);
      o.h[2] = __float2bfloat16(u0.z * scale);
      o.h[3] = __float2bfloat16(u0.w * scale);
      o.h[4] = __float2bfloat16(u1.x * scale);
      o.h[5] = __float2bfloat16(u1.y * scale);
      o.h[6] = __float2bfloat16(u1.z * scale);
      o.h[7] = __float2bfloat16(u1.w * scale);
      // granule address: ((b*96 + kc)*128 + t) * 8 ushorts
      *reinterpret_cast<short8*>(xn2p + ((size_t)(b * 96 + tid) * 128 + t) * 8) = o.s;
    }
  }
}

// A-stage: 2 gload_lds/thread into buf BUF (16 KB tile). Linear LDS dest,
// inverse-swizzled GLOBAL source chunk (rule 21).
#define STAGE_A(KN, BUF)                                          \
  {                                                               \
    gload_lds16(Ag + asrc0 + (KN), Al + (BUF)*8192 + ad0);        \
    gload_lds16(Ag + asrc1 + (KN), Al + (BUF)*8192 + ad1);        \
  }

// B fragments for K-tile at elem offset KN -> regs. Packed layout: addr =
// Bpk + KN*128 + kf*4096 + j*128 (ushort units); 16 lanes (rl) are 256B
// contiguous per g-group -> 4 dense segments per instruction.
#define LOADB(BV, KN)                                                        \
  {                                                                          \
    _Pragma("unroll")                                                        \
    for (int kf = 0; kf < 2; ++kf)                                           \
      _Pragma("unroll")                                                      \
      for (int j = 0; j < 4; ++j)                                            \
        BV[kf][j] = *reinterpret_cast<const short8*>(                        \
            Bpk + (size_t)(KN)*128 + kf * 4096 + j * 128);                   \
  }

// One K-tile step: {prefetch A(kt+1)->LDS[NXT] (2 vmem) then B(kt+1)->BVN
// (8 vmem) | compute kt from LDS[CUR] x BVC | vmcnt(8): A retired, B flies |
// barrier}. Per-wave vmcnt BEFORE the barrier closes the cross-wave RAW on
// LDS[NXT]; barrier separates step-t reads of LDS[CUR] from step-t+1 writes.
#define STEP(CUR, NXT, BVC, BVN, KT, PF)                                      \
  {                                                                           \
    if (PF) {                                                                 \
      const int kn = ((KT) + 1) * BK;                                         \
      STAGE_A(kn, NXT);                                                       \
      __builtin_amdgcn_sched_barrier(0); /* pin A-issue before B-issue */     \
      LOADB(BVN, kn);                                                         \
      __builtin_amdgcn_sched_barrier(0);                                      \
    }                                                                         \
    _Pragma("unroll")                                                         \
    for (int kf = 0; kf < 2; ++kf) {                                          \
      short8 av[4];                                                           \
      _Pragma("unroll")                                                       \
      for (int i = 0; i < 4; ++i) {                                           \
        const int r = wm * 64 + i * 16 + rl;                                  \
        const int slot = (kf * 4 + g) ^ (r & 7); /* swizzled read */          \
        av[i] = *reinterpret_cast<const short8*>(&Al[(CUR)*8192 + r * 64 + slot * 8]); \
      }                                                                       \
      __builtin_amdgcn_s_setprio(1);                                          \
      _Pragma("unroll")                                                       \
      for (int i = 0; i < 4; ++i)                                             \
        _Pragma("unroll")                                                     \
        for (int j = 0; j < 4; ++j)                                           \
          acc[i][j] = __builtin_amdgcn_mfma_f32_16x16x32_bf16(                \
              av[i], BVC[kf][j], acc[i][j], 0, 0, 0);                         \
      __builtin_amdgcn_s_setprio(0);                                          \
    }                                                                         \
    if (PF) {                                                                 \
      asm volatile("s_waitcnt vmcnt(8)" ::: "memory");                        \
      __builtin_amdgcn_s_barrier();                                           \
    }                                                                         \
  }

// ---------------- Kernel 2: one block = (a, {b0,b1}), 128x256 tile ----------------
// 8 waves 2x4: wave (wm,wn) owns rows wm*64..+64, cols wn*64..+64.
// A double-buffered in LDS (32 KB); B double-buffered in REGISTERS from the
// fragment-packed xn2p (dense 256B segments).
__global__ __launch_bounds__(512, 2) void rwmd_kernel(
    const unsigned short* __restrict__ xn1, const unsigned short* __restrict__ xn2p,
    const int* __restrict__ mask1, const int* __restrict__ mask2,
    float* __restrict__ out) {
  __shared__ __align__(16) unsigned short Al[2 * S_LEN * BK];  // 32 KB, 2 bufs
  __shared__ int m1s[S_LEN], m2s[2 * S_LEN];
  __shared__ float rpart[4][S_LEN];      // [wn][row] partial row-max
  __shared__ float cpart[2][2 * S_LEN];  // [wm][col] partial col-max

  const int a = blockIdx.x >> 5;   // 64 a's
  const int bp = blockIdx.x & 31;  // 32 b-pairs
  const int tid = threadIdx.x;
  const int lane = tid & 63;
  const int w = tid >> 6;
  const int wm = w >> 2, wn = w & 3;
  const int g = lane >> 4, rl = lane & 15;

  const unsigned short* Ag = xn1 + (size_t)a * (S_LEN * H_DIM);

  if (tid < S_LEN) m1s[tid] = mask1[a * S_LEN + tid];
  else if (tid < 3 * S_LEN) m2s[tid - S_LEN] = mask2[bp * 2 * S_LEN + (tid - S_LEN)];

  // per-thread A-stage addressing (chunk s = q*512+tid; row = s>>3; src chunk XOR-swizzled)
  const int s0 = tid, s1 = 512 + tid;
  const int ar0 = s0 >> 3, ar1 = s1 >> 3;
  const size_t asrc0 = (size_t)ar0 * H_DIM + (size_t)(((s0 & 7) ^ (ar0 & 7)) * 8);
  const size_t asrc1 = (size_t)ar1 * H_DIM + (size_t)(((s1 & 7) ^ (ar1 & 7)) * 8);
  const int ad0 = s0 * 8, ad1 = s1 * 8;

  // packed-B per-lane base: panel b = bp*2 + (wn>>1); token tB = (wn&1)*64 + rl;
  // + g granule offset. Granule = 8 ushorts; [b][kc][t] with kc-stride 128*8.
  const unsigned short* Bpk = xn2p +
      ((size_t)(bp * 2 + (wn >> 1)) * 96 + g) * 1024 + ((wn & 1) * 64 + rl) * 8;

  f32x4 acc[4][4];
#pragma unroll
  for (int i = 0; i < 4; ++i)
#pragma unroll
    for (int j = 0; j < 4; ++j) acc[i][j] = (f32x4){0.f, 0.f, 0.f, 0.f};
  short8 bva[2][4], bvb[2][4];

  // prologue: tile 0 (A->LDS buf0, B->bva); full drain once per block
  STAGE_A(0, 0);
  __builtin_amdgcn_sched_barrier(0);
  LOADB(bva, 0);
  asm volatile("s_waitcnt vmcnt(0)" ::: "memory");
  __builtin_amdgcn_s_barrier();

#pragma unroll 1
  for (int t = 0; t < NT / 2; ++t) {
    STEP(0, 1, bva, bvb, 2 * t, true);          // kt even: 0..10, always prefetch
    STEP(1, 0, bvb, bva, 2 * t + 1, (t < 5));   // kt odd: last (11) has no prefetch
  }

  // ---- in-register masked reductions ----
  // acc[i][j][r]: row = wm*64 + i*16 + g*4 + r, col = wn*64 + j*16 + rl
#pragma unroll
  for (int i = 0; i < 4; ++i) {
#pragma unroll
    for (int r = 0; r < 4; ++r) {
      float pm = -INFINITY;
#pragma unroll
      for (int j = 0; j < 4; ++j) {
        const int col = wn * 64 + j * 16 + rl;
        pm = fmaxf(pm, m2s[col] ? acc[i][j][r] : -INFINITY);
      }
#pragma unroll
      for (int o = 1; o < 16; o <<= 1) pm = fmaxf(pm, __shfl_xor(pm, o));
      if (rl == 0) rpart[wn][wm * 64 + i * 16 + g * 4 + r] = pm;
    }
  }
#pragma unroll
  for (int j = 0; j < 4; ++j) {
    float cm = -INFINITY;
#pragma unroll
    for (int i = 0; i < 4; ++i)
#pragma unroll
      for (int r = 0; r < 4; ++r) {
        const int row = wm * 64 + i * 16 + g * 4 + r;
        cm = fmaxf(cm, m1s[row] ? acc[i][j][r] : -INFINITY);
      }
    cm = fmaxf(cm, __shfl_xor(cm, 16));
    cm = fmaxf(cm, __shfl_xor(cm, 32));
    if (g == 0) cpart[wm][wn * 64 + j * 16 + rl] = cm;
  }
  __syncthreads();

  // ---- final masked means: wave 0 -> b0, wave 1 -> b1 ----
  if (w < 2) {
    float v1 = 0.f, c1 = 0.f, v2 = 0.f, c2 = 0.f;
#pragma unroll
    for (int t = 0; t < 2; ++t) {
      const int r = lane + t * 64;
      if (m1s[r]) { v1 += fmaxf(rpart[2 * w][r], rpart[2 * w + 1][r]); c1 += 1.f; }
      const int c = w * 128 + lane + t * 64;
      if (m2s[c]) { v2 += fmaxf(cpart[0][c], cpart[1][c]); c2 += 1.f; }
    }
#pragma unroll
    for (int o = 32; o > 0; o >>= 1) {
      v1 += __shfl_down(v1, o); c1 += __shfl_down(c1, o);
      v2 += __shfl_down(v2, o); c2 += __shfl_down(c2, o);
    }
    if (lane == 0) out[a * 64 + bp * 2 + w] = 0.5f * (v1 / c1 + v2 / c2);
  }
}

extern "C" void kernel_launch(void* const* d_in, const int* in_sizes, int n_in,
                              void* d_out, int out_size, void* d_ws, size_t ws_size,
                              hipStream_t stream) {
  const float* x1 = (const float*)d_in[0];
  const int* mask1 = (const int*)d_in[1];
  const float* x2 = (const float*)d_in[2];
  const int* mask2 = (const int*)d_in[3];
  float* out = (float*)d_out;

  unsigned short* xn1 = (unsigned short*)d_ws;          // 12.6 MB row-major A
  unsigned short* xn2p = xn1 + (size_t)64 * 128 * 768;  // 12.6 MB fragment-packed B

  norm_bf16_kernel<<<16384, 256, 0, stream>>>(x1, x2, xn1, xn2p);
  rwmd_kernel<<<64 * 32, 512, 0, stream>>>(xn1, xn2p, mask1, mask2, out);
}

// Round 9
// 154.364 us; speedup vs baseline: 3.7853x; 1.1042x over previous
//
#include <hip/hip_runtime.h>
#include <hip/hip_bf16.h>

#define H_DIM 768
#define S_LEN 128
#define BK 64
#define NT 12  // 768 / 64 K-tiles

typedef __attribute__((ext_vector_type(8))) short short8;
typedef __attribute__((ext_vector_type(4))) float f32x4;

__device__ __forceinline__ void gload_lds16(const void* g, void* l) {
  __builtin_amdgcn_global_load_lds(
      (const __attribute__((address_space(1))) unsigned int*)g,
      (__attribute__((address_space(3))) unsigned int*)l, 16, 0, 0);
}

// ---------------- Kernel 1: per-token L2 normalize, fp32 -> bf16 ----------------
// x1 -> row-major xn1 (A operand, staged via DMA).
// x2 -> FRAGMENT-PACKED xn2p: granule layout [b][kc][t], kc = K/8 (96), t = token
// (128), 16B granules -> bv loads read dense 256B segments.
__global__ __launch_bounds__(256) void norm_bf16_kernel(
    const float* __restrict__ x1, const float* __restrict__ x2,
    unsigned short* __restrict__ xn1, unsigned short* __restrict__ xn2p) {
  const int gid = blockIdx.x;
  const bool isA = (gid < 8192);
  const float* row = isA ? (x1 + (size_t)gid * H_DIM)
                         : (x2 + (size_t)(gid - 8192) * H_DIM);
  const int tid = threadIdx.x;
  float4 v = make_float4(0.f, 0.f, 0.f, 0.f);
  float ss = 0.f;
  if (tid < 192) {
    v = reinterpret_cast<const float4*>(row)[tid];
    ss = v.x * v.x + v.y * v.y + v.z * v.z + v.w * v.w;
  }
#pragma unroll
  for (int o = 32; o > 0; o >>= 1) ss += __shfl_down(ss, o);
  __shared__ float ws[4];
  if ((tid & 63) == 0) ws[tid >> 6] = ss;
  __syncthreads();
  const float scale = 1.0f / sqrtf(ws[0] + ws[1] + ws[2] + ws[3]);
  if (isA) {
    if (tid < 192) {
      union { ushort4 u; __hip_bfloat16 h[4]; } o;
      o.h[0] = __float2bfloat16(v.x * scale);
      o.h[1] = __float2bfloat16(v.y * scale);
      o.h[2] = __float2bfloat16(v.z * scale);
      o.h[3] = __float2bfloat16(v.w * scale);
      reinterpret_cast<ushort4*>(xn1 + (size_t)gid * H_DIM)[tid] = o.u;
    }
  } else {
    const int tok = gid - 8192;
    const int b = tok >> 7, t = tok & 127;
    if (tid < 96) {  // one 16B granule (8 elems) per thread
      const float4 u0 = reinterpret_cast<const float4*>(row)[tid * 2];
      const float4 u1 = reinterpret_cast<const float4*>(row)[tid * 2 + 1];
      union { short8 s; __hip_bfloat16 h[8]; } o;
      o.h[0] = __float2bfloat16(u0.x * scale);
      o.h[1] = __float2bfloat16(u0.y * scale);
      o.h[2] = __float2bfloat16(u0.z * scale);
      o.h[3] = __float2bfloat16(u0.w * scale);
      o.h[4] = __float2bfloat16(u1.x * scale);
      o.h[5] = __float2bfloat16(u1.y * scale);
      o.h[6] = __float2bfloat16(u1.z * scale);
      o.h[7] = __float2bfloat16(u1.w * scale);
      *reinterpret_cast<short8*>(xn2p + ((size_t)(b * 96 + tid) * 128 + t) * 8) = o.s;
    }
  }
}

// A-stage: 2 gload_lds/thread into buf BUF (16 KB = 128x64 tile). Linear LDS
// dest, inverse-swizzled GLOBAL source chunk (rule 21).
#define STAGE_A(KN, BUF)                                          \
  {                                                               \
    gload_lds16(Ag + asrc0 + (KN), Al + (BUF)*8192 + ad0);        \
    gload_lds16(Ag + asrc1 + (KN), Al + (BUF)*8192 + ad1);        \
  }

// B fragments for K-tile at elem offset KN -> regs (4 loads, dense 256B segs).
// addr = Bpk + KN*128 + kf*4096 + j*128 (ushort units).
#define LOADB(BV, KN)                                                        \
  {                                                                          \
    _Pragma("unroll")                                                        \
    for (int kf = 0; kf < 2; ++kf)                                           \
      _Pragma("unroll")                                                      \
      for (int j = 0; j < 2; ++j)                                            \
        BV[kf][j] = *reinterpret_cast<const short8*>(                        \
            Bpk + (size_t)(KN)*128 + kf * 4096 + j * 128);                   \
  }

// One K-tile step: {prefetch A(kt+1)->LDS[NXT] (2 vmem) then B(kt+1)->BVN
// (4 vmem) | compute kt from LDS[CUR] x BVC | vmcnt(4): A retired, B flies |
// barrier}. MFMA consumption forces av ds_read retirement before the barrier,
// so next step's write of LDS[NXT] is WAR-safe; per-wave vmcnt BEFORE the
// barrier closes the cross-wave RAW on LDS[NXT].
#define STEP(CUR, NXT, BVC, BVN, KT, PF)                                      \
  {                                                                           \
    if (PF) {                                                                 \
      const int kn = ((KT) + 1) * BK;                                         \
      STAGE_A(kn, NXT);                                                       \
      __builtin_amdgcn_sched_barrier(0); /* pin A-issue before B-issue */     \
      LOADB(BVN, kn);                                                         \
      __builtin_amdgcn_sched_barrier(0);                                      \
    }                                                                         \
    _Pragma("unroll")                                                         \
    for (int kf = 0; kf < 2; ++kf) {                                          \
      short8 av[4];                                                           \
      _Pragma("unroll")                                                       \
      for (int i = 0; i < 4; ++i) {                                           \
        const int r = wm * 64 + i * 16 + rl;                                  \
        const int slot = (kf * 4 + g) ^ (r & 7); /* swizzled read */          \
        av[i] = *reinterpret_cast<const short8*>(&Al[(CUR)*8192 + r * 64 + slot * 8]); \
      }                                                                       \
      __builtin_amdgcn_s_setprio(1);                                          \
      _Pragma("unroll")                                                       \
      for (int i = 0; i < 4; ++i)                                             \
        _Pragma("unroll")                                                     \
        for (int j = 0; j < 2; ++j)                                           \
          acc[i][j] = __builtin_amdgcn_mfma_f32_16x16x32_bf16(                \
              av[i], BVC[kf][j], acc[i][j], 0, 0, 0);                         \
      __builtin_amdgcn_s_setprio(0);                                          \
    }                                                                         \
    if (PF) {                                                                 \
      asm volatile("s_waitcnt vmcnt(4)" ::: "memory");                        \
      __builtin_amdgcn_s_barrier();                                           \
    }                                                                         \
  }

// ---------------- Kernel 2: one block = one (a,b) pair, 128x128 tile ----------------
// 8 waves 2x4: wave (wm,wn) owns rows wm*64..+64, cols wn*32..+32 (4i x 2j frags).
// acc = 32 AGPR; bv dbuf = 32 VGPR; total regs ~120 <= 128 -> 2 blocks/CU
// (16 waves) — the round-2 operating point, with half the acc and B off LDS.
__global__ __launch_bounds__(512, 4) void rwmd_kernel(
    const unsigned short* __restrict__ xn1, const unsigned short* __restrict__ xn2p,
    const int* __restrict__ mask1, const int* __restrict__ mask2,
    float* __restrict__ out) {
  // 2 bufs x (128x64 bf16 = 16 KB) = 32 KB. Round 8 had a stray /2 here ->
  // buf1 overflowed into the mask arrays (DMA clobber) -> absmax 1.5e-2.
  __shared__ __align__(16) unsigned short Al[2 * S_LEN * BK];
  __shared__ int m1s[S_LEN], m2s[S_LEN];
  __shared__ float rpart[4][S_LEN];  // [wn][row] partial row-max
  __shared__ float cpart[2][S_LEN];  // [wm][col] partial col-max

  const int a = blockIdx.x >> 6;  // 64 a's
  const int b = blockIdx.x & 63;  // 64 b's
  const int tid = threadIdx.x;
  const int lane = tid & 63;
  const int w = tid >> 6;
  const int wm = w >> 2, wn = w & 3;
  const int g = lane >> 4, rl = lane & 15;

  const unsigned short* Ag = xn1 + (size_t)a * (S_LEN * H_DIM);

  if (tid < S_LEN) m1s[tid] = mask1[a * S_LEN + tid];
  else if (tid < 2 * S_LEN) m2s[tid - S_LEN] = mask2[b * S_LEN + (tid - S_LEN)];

  // per-thread A-stage addressing (chunk s = q*512+tid; row = s>>3 in 0..127)
  const int s0 = tid, s1 = 512 + tid;
  const int ar0 = s0 >> 3, ar1 = s1 >> 3;
  const size_t asrc0 = (size_t)ar0 * H_DIM + (size_t)(((s0 & 7) ^ (ar0 & 7)) * 8);
  const size_t asrc1 = (size_t)ar1 * H_DIM + (size_t)(((s1 & 7) ^ (ar1 & 7)) * 8);
  const int ad0 = s0 * 8, ad1 = s1 * 8;

  // packed-B per-lane base: token t = wn*32 + rl, + g granule offset.
  const unsigned short* Bpk = xn2p +
      ((size_t)b * 96 + g) * 1024 + (wn * 32 + rl) * 8;

  f32x4 acc[4][2];
#pragma unroll
  for (int i = 0; i < 4; ++i)
#pragma unroll
    for (int j = 0; j < 2; ++j) acc[i][j] = (f32x4){0.f, 0.f, 0.f, 0.f};
  short8 bva[2][2], bvb[2][2];

  // prologue: tile 0 (A->LDS buf0, B->bva); full drain once per block
  STAGE_A(0, 0);
  __builtin_amdgcn_sched_barrier(0);
  LOADB(bva, 0);
  asm volatile("s_waitcnt vmcnt(0) lgkmcnt(0)" ::: "memory");  // lgkm: mask ds_writes
  __builtin_amdgcn_s_barrier();

#pragma unroll 1
  for (int t = 0; t < NT / 2; ++t) {
    STEP(0, 1, bva, bvb, 2 * t, true);          // even tiles 0..10: always prefetch
    STEP(1, 0, bvb, bva, 2 * t + 1, (t < 5));   // odd tiles; last (11) no prefetch
  }

  // ---- in-register masked reductions ----
  // acc[i][j][r]: row = wm*64 + i*16 + g*4 + r, col = wn*32 + j*16 + rl
#pragma unroll
  for (int i = 0; i < 4; ++i) {
#pragma unroll
    for (int r = 0; r < 4; ++r) {
      float pm = -INFINITY;
#pragma unroll
      for (int j = 0; j < 2; ++j) {
        const int col = wn * 32 + j * 16 + rl;
        pm = fmaxf(pm, m2s[col] ? acc[i][j][r] : -INFINITY);
      }
#pragma unroll
      for (int o = 1; o < 16; o <<= 1) pm = fmaxf(pm, __shfl_xor(pm, o));
      if (rl == 0) rpart[wn][wm * 64 + i * 16 + g * 4 + r] = pm;
    }
  }
#pragma unroll
  for (int j = 0; j < 2; ++j) {
    float cm = -INFINITY;
#pragma unroll
    for (int i = 0; i < 4; ++i)
#pragma unroll
      for (int r = 0; r < 4; ++r) {
        const int row = wm * 64 + i * 16 + g * 4 + r;
        cm = fmaxf(cm, m1s[row] ? acc[i][j][r] : -INFINITY);
      }
    cm = fmaxf(cm, __shfl_xor(cm, 16));
    cm = fmaxf(cm, __shfl_xor(cm, 32));
    if (g == 0) cpart[wm][wn * 32 + j * 16 + rl] = cm;
  }
  __syncthreads();

  // ---- final masked means on wave 0 ----
  if (w == 0) {
    float v1 = 0.f, c1 = 0.f, v2 = 0.f, c2 = 0.f;
#pragma unroll
    for (int t = 0; t < 2; ++t) {
      const int r = lane + t * 64;
      if (m1s[r]) {
        v1 += fmaxf(fmaxf(rpart[0][r], rpart[1][r]), fmaxf(rpart[2][r], rpart[3][r]));
        c1 += 1.f;
      }
      if (m2s[r]) { v2 += fmaxf(cpart[0][r], cpart[1][r]); c2 += 1.f; }
    }
#pragma unroll
    for (int o = 32; o > 0; o >>= 1) {
      v1 += __shfl_down(v1, o); c1 += __shfl_down(c1, o);
      v2 += __shfl_down(v2, o); c2 += __shfl_down(c2, o);
    }
    if (lane == 0) out[a * 64 + b] = 0.5f * (v1 / c1 + v2 / c2);
  }
}

extern "C" void kernel_launch(void* const* d_in, const int* in_sizes, int n_in,
                              void* d_out, int out_size, void* d_ws, size_t ws_size,
                              hipStream_t stream) {
  const float* x1 = (const float*)d_in[0];
  const int* mask1 = (const int*)d_in[1];
  const float* x2 = (const float*)d_in[2];
  const int* mask2 = (const int*)d_in[3];
  float* out = (float*)d_out;

  unsigned short* xn1 = (unsigned short*)d_ws;          // 12.6 MB row-major A
  unsigned short* xn2p = xn1 + (size_t)64 * 128 * 768;  // 12.6 MB fragment-packed B

  norm_bf16_kernel<<<16384, 256, 0, stream>>>(x1, x2, xn1, xn2p);
  rwmd_kernel<<<64 * 64, 512, 0, stream>>>(xn1, xn2p, mask1, mask2, out);
}

// Round 10
// 121.582 us; speedup vs baseline: 4.8059x; 1.2696x over previous
//
#include <hip/hip_runtime.h>
#include <hip/hip_bf16.h>

#define H_DIM 768
#define S_LEN 128
#define BK 64

typedef __attribute__((ext_vector_type(8))) short short8;
typedef __attribute__((ext_vector_type(4))) float f32x4;

__device__ __forceinline__ void gload_lds16(const void* g, void* l) {
  __builtin_amdgcn_global_load_lds(
      (const __attribute__((address_space(1))) unsigned int*)g,
      (__attribute__((address_space(3))) unsigned int*)l, 16, 0, 0);
}

// ---------------- Kernel 1: per-token L2 normalize, fp32 -> bf16 (both tensors) ----------------
__global__ __launch_bounds__(256) void norm_bf16_kernel(
    const float* __restrict__ x1, const float* __restrict__ x2,
    unsigned short* __restrict__ xn1, unsigned short* __restrict__ xn2) {
  const int gid = blockIdx.x;
  const float* row;
  unsigned short* orow;
  if (gid < 8192) { row = x1 + (size_t)gid * H_DIM; orow = xn1 + (size_t)gid * H_DIM; }
  else            { row = x2 + (size_t)(gid - 8192) * H_DIM; orow = xn2 + (size_t)(gid - 8192) * H_DIM; }
  const int tid = threadIdx.x;
  float4 v = make_float4(0.f, 0.f, 0.f, 0.f);
  float ss = 0.f;
  if (tid < 192) {  // 192 * 4 = 768 floats
    v = reinterpret_cast<const float4*>(row)[tid];
    ss = v.x * v.x + v.y * v.y + v.z * v.z + v.w * v.w;
  }
#pragma unroll
  for (int o = 32; o > 0; o >>= 1) ss += __shfl_down(ss, o);
  __shared__ float ws[4];
  if ((tid & 63) == 0) ws[tid >> 6] = ss;
  __syncthreads();
  const float scale = 1.0f / sqrtf(ws[0] + ws[1] + ws[2] + ws[3]);
  if (tid < 192) {
    union { ushort4 u; __hip_bfloat16 h[4]; } o;
    o.h[0] = __float2bfloat16(v.x * scale);
    o.h[1] = __float2bfloat16(v.y * scale);
    o.h[2] = __float2bfloat16(v.z * scale);
    o.h[3] = __float2bfloat16(v.w * scale);
    reinterpret_cast<ushort4*>(orow)[tid] = o.u;
  }
}

// ---------------- Kernel 2: one block = pair-batch (a, {b0,b1}), 128x256 tile ----------------
// EXACT round-2 structure (proven 109.5 us / MfmaUtil 40% at 2 blocks/CU), with
// an LDS diet to reach 3 blocks/CU (48 KB/block): masks live in packed bitmask
// REGISTERS (loaded from L2 in the epilogue), and the rpart/cpart reduction
// arrays OVERLAY the dead staging buffers after a final barrier.
__global__ __launch_bounds__(512, 2) void rwmd_kernel(
    const unsigned short* __restrict__ xn1, const unsigned short* __restrict__ xn2,
    const int* __restrict__ mask1, const int* __restrict__ mask2,
    float* __restrict__ out) {
  __shared__ __align__(16) unsigned char smem[49152];          // 48 KB exactly
  unsigned short* const Al = (unsigned short*)smem;            // [128][64] bf16, 16 KB
  unsigned short* const Bl = (unsigned short*)(smem + 16384);  // [256][64] bf16, 32 KB
  float* const rpart = (float*)smem;                           // overlay: [4][128] row-max
  float* const cpart = (float*)(smem + 2048);                  // overlay: [2][256] col-max

  const int a = blockIdx.x >> 5;        // 64 a's
  const int bp = blockIdx.x & 31;       // 32 b-pairs
  const int b0 = bp * 2;
  const int tid = threadIdx.x;
  const int lane = tid & 63;
  const int w = tid >> 6;
  const int wm = w >> 2, wn = w & 3;
  const int g = lane >> 4, rl = lane & 15;

  const unsigned short* A0 = xn1 + (size_t)a * (S_LEN * H_DIM);
  const unsigned short* B0 = xn2 + (size_t)b0 * (S_LEN * H_DIM);  // b0,b1 contiguous: 256 rows

  f32x4 acc[4][4];
#pragma unroll
  for (int i = 0; i < 4; ++i)
#pragma unroll
    for (int j = 0; j < 4; ++j) acc[i][j] = (f32x4){0.f, 0.f, 0.f, 0.f};

  for (int k0 = 0; k0 < H_DIM; k0 += BK) {
    __syncthreads();  // previous compute done before DMA overwrites LDS
    // A: 1024 16B-chunks, B: 2048 chunks; 6 per thread. Linear LDS dest,
    // inverse-swizzled global source (rule 21).
#pragma unroll
    for (int t = 0; t < 2; ++t) {
      const int s = t * 512 + tid;
      const int row = s >> 3;
      const int cb = (s & 7) ^ (row & 7);
      gload_lds16(A0 + (size_t)row * H_DIM + k0 + cb * 8, Al + s * 8);
    }
#pragma unroll
    for (int t = 0; t < 4; ++t) {
      const int s = t * 512 + tid;
      const int row = s >> 3;  // 0..255
      const int cb = (s & 7) ^ (row & 7);
      gload_lds16(B0 + (size_t)row * H_DIM + k0 + cb * 8, Bl + s * 8);
    }
    __syncthreads();  // compiler drains vmcnt(0) before barrier
#pragma unroll
    for (int kf = 0; kf < 2; ++kf) {
      short8 av[4], bv[4];
#pragma unroll
      for (int i = 0; i < 4; ++i) {
        const int r = wm * 64 + i * 16 + rl;
        const int slot = (kf * 4 + g) ^ (r & 7);  // swizzled read
        av[i] = *reinterpret_cast<const short8*>(&Al[r * BK + slot * 8]);
      }
#pragma unroll
      for (int j = 0; j < 4; ++j) {
        const int r = wn * 64 + j * 16 + rl;  // 0..255
        const int slot = (kf * 4 + g) ^ (r & 7);
        bv[j] = *reinterpret_cast<const short8*>(&Bl[r * BK + slot * 8]);
      }
#pragma unroll
      for (int i = 0; i < 4; ++i)
#pragma unroll
        for (int j = 0; j < 4; ++j)
          acc[i][j] = __builtin_amdgcn_mfma_f32_16x16x32_bf16(av[i], bv[j], acc[i][j], 0, 0, 0);
    }
  }

  // ---- per-thread packed mask bits from global (L2-hot; 20 dword loads) ----
  __builtin_amdgcn_sched_barrier(0);  // keep these out of the K-loop region
  unsigned mcol = 0, mrow = 0;
#pragma unroll
  for (int j = 0; j < 4; ++j)
    mcol |= (mask2[b0 * S_LEN + wn * 64 + j * 16 + rl] ? 1u : 0u) << j;
#pragma unroll
  for (int i = 0; i < 4; ++i)
#pragma unroll
    for (int r = 0; r < 4; ++r)
      mrow |= (mask1[a * S_LEN + wm * 64 + i * 16 + g * 4 + r] ? 1u : 0u) << (i * 4 + r);

  __syncthreads();  // staging LDS now dead -> safe to overlay rpart/cpart

  // ---- in-register masked reductions ----
  // acc[i][j][r]: row = wm*64 + i*16 + g*4 + r, col = wn*64 + j*16 + rl
#pragma unroll
  for (int i = 0; i < 4; ++i) {
#pragma unroll
    for (int r = 0; r < 4; ++r) {
      float pm = -INFINITY;
#pragma unroll
      for (int j = 0; j < 4; ++j)
        pm = fmaxf(pm, ((mcol >> j) & 1) ? acc[i][j][r] : -INFINITY);
#pragma unroll
      for (int o = 1; o < 16; o <<= 1) pm = fmaxf(pm, __shfl_xor(pm, o));
      if (rl == 0) rpart[wn * S_LEN + wm * 64 + i * 16 + g * 4 + r] = pm;
    }
  }
#pragma unroll
  for (int j = 0; j < 4; ++j) {
    float cm = -INFINITY;
#pragma unroll
    for (int i = 0; i < 4; ++i)
#pragma unroll
      for (int r = 0; r < 4; ++r)
        cm = fmaxf(cm, ((mrow >> (i * 4 + r)) & 1) ? acc[i][j][r] : -INFINITY);
    cm = fmaxf(cm, __shfl_xor(cm, 16));
    cm = fmaxf(cm, __shfl_xor(cm, 32));
    if (g == 0) cpart[wm * 256 + wn * 64 + j * 16 + rl] = cm;
  }
  __syncthreads();

  // ---- final masked means: wave 0 -> pair b0, wave 1 -> pair b1 ----
  if (w < 2) {
    float v1 = 0.f, c1 = 0.f, v2 = 0.f, c2 = 0.f;
#pragma unroll
    for (int t = 0; t < 2; ++t) {
      const int r = lane + t * 64;
      if (mask1[a * S_LEN + r]) {
        v1 += fmaxf(rpart[(2 * w) * S_LEN + r], rpart[(2 * w + 1) * S_LEN + r]);
        c1 += 1.f;
      }
      const int c = w * 128 + lane + t * 64;
      if (mask2[b0 * S_LEN + c]) {
        v2 += fmaxf(cpart[c], cpart[256 + c]);
        c2 += 1.f;
      }
    }
#pragma unroll
    for (int o = 32; o > 0; o >>= 1) {
      v1 += __shfl_down(v1, o); c1 += __shfl_down(c1, o);
      v2 += __shfl_down(v2, o); c2 += __shfl_down(c2, o);
    }
    if (lane == 0) out[a * 64 + b0 + w] = 0.5f * (v1 / c1 + v2 / c2);
  }
}

extern "C" void kernel_launch(void* const* d_in, const int* in_sizes, int n_in,
                              void* d_out, int out_size, void* d_ws, size_t ws_size,
                              hipStream_t stream) {
  const float* x1 = (const float*)d_in[0];
  const int* mask1 = (const int*)d_in[1];
  const float* x2 = (const float*)d_in[2];
  const int* mask2 = (const int*)d_in[3];
  float* out = (float*)d_out;

  unsigned short* xn1 = (unsigned short*)d_ws;         // 64*128*768 bf16
  unsigned short* xn2 = xn1 + (size_t)64 * 128 * 768;  // 12.6 MB each

  norm_bf16_kernel<<<16384, 256, 0, stream>>>(x1, x2, xn1, xn2);
  rwmd_kernel<<<64 * 32, 512, 0, stream>>>(xn1, xn2, mask1, mask2, out);
}